// Round 4
// baseline (757.281 us; speedup 1.0000x reference)
//
#include <hip/hip_runtime.h>
#include <math.h>

#define NB 16
#define SL 2048
#define HD 64
#define TQ 16
#define BK 64
#define NT (SL / BK)          // 32 k-tiles
#define SC2 0.18033688f       // (1/TEMPERATURE) * log2(e): exp(s/8) = exp2(s*SC2)
#define SSTRIDE 2056          // fp16 elems per S row (2048 + 8 pad, 16B-aligned rows)

typedef _Float16 half8 __attribute__((ext_vector_type(8)));
typedef float floatx4 __attribute__((ext_vector_type(4)));
typedef int intx4 __attribute__((ext_vector_type(4)));

__device__ __forceinline__ half8 load_frag_f32(const float* p) {
  floatx4 f0 = *(const floatx4*)p;
  floatx4 f1 = *(const floatx4*)(p + 4);
  half8 h;
  h[0] = (_Float16)f0[0]; h[1] = (_Float16)f0[1];
  h[2] = (_Float16)f0[2]; h[3] = (_Float16)f0[3];
  h[4] = (_Float16)f1[0]; h[5] = (_Float16)f1[1];
  h[6] = (_Float16)f1[2]; h[7] = (_Float16)f1[3];
  return h;
}

// Small pre-pass (512 blocks, ~10 us): K -> KH (f16, [b][k][d]), V -> VT (f16,
// transposed [b][d][k]). The mask pack kernel is GONE (round-4): masks are now
// streamed inline by attn blocks, overlapping their compute.
__global__ __launch_bounds__(256) void prep_kernel(
    const float* __restrict__ K, const float* __restrict__ V,
    _Float16* __restrict__ KH, _Float16* __restrict__ VT)
{
  __shared__ __align__(16) _Float16 tile[64][72];   // V tile, 16-chunk XOR swizzle
  const int bid = blockIdx.x;
  const int t   = (int)threadIdx.x;
  const int k0 = (bid & 31) * 64;
  const int b  = bid >> 5;
  const size_t base = (size_t)b * SL * HD;
  const int r  = t >> 2;
  const int cq = (t & 3) * 16;

  const float* kp = K + base + (size_t)(k0 + r) * HD + cq;
  const float* vp = V + base + (size_t)(k0 + r) * HD + cq;
  half8 kh0 = load_frag_f32(kp), kh1 = load_frag_f32(kp + 8);
  half8 vh0 = load_frag_f32(vp), vh1 = load_frag_f32(vp + 8);

  _Float16* khp = KH + base + (size_t)(k0 + r) * HD + cq;
  *(half8*)khp       = kh0;
  *(half8*)(khp + 8) = kh1;

  const int wc = cq ^ (((r >> 4) & 3) * 16);
  *(half8*)&tile[r][wc]     = vh0;
  *(half8*)&tile[r][wc + 8] = vh1;
  __syncthreads();

  const int sx = ((cq >> 4) & 3) * 16;
  half8 o0, o1;
  #pragma unroll
  for (int i = 0; i < 8; ++i) {
    o0[i] = tile[cq + i][r ^ sx];
    o1[i] = tile[cq + 8 + i][r ^ sx];
  }
  _Float16* vt = VT + (size_t)b * HD * SL + (size_t)r * SL + k0 + cq;
  *(half8*)vt       = o0;
  *(half8*)(vt + 8) = o1;
}

// One block = 16 q-rows of one batch, 512 threads = 8 waves, 2 blocks/CU.
// Round-4 structure:
//  - ENTRY: inline mask stream+pack. Thread (row16,ci) loads EXACTLY the mask words
//    its P1 slice needs (c = it*256+ci*8, perfectly coalesced), packs keep = dm & ~mk
//    to 1 bit/col immediately -> one u64/thread. Two 4-iteration batches bound peak
//    live mask regs to ~64 VGPRs, all dead before Phase A (round-1 lesson: never hold
//    raw mask regs across Phase A). The 512 MB stream overlaps Phase A/PV via TLP.
//  - Phase A: plain QK^T -> S (round-3 fusion reverted: it regressed 20 us).
//  - P1: mask bytes from the register u64, exp2, row-sum. No global loads, no shuffles.
//  - PV: MFMA with interleaved normalized attn stores; cross-half merge via LDS.
// MODE 2: f16 KH/VT from workspace. MODE 1: no workspace (f32 K, scalar V gathers).
template <int MODE>
__global__ __launch_bounds__(512, 4) void attn_kernel(
    const float* __restrict__ Q, const float* __restrict__ K,
    const float* __restrict__ V, const _Float16* __restrict__ KH,
    const _Float16* __restrict__ VT,
    const int* __restrict__ DM, const int* __restrict__ MMk,
    float* __restrict__ Out, float* __restrict__ Attn)
{
  const int qt    = blockIdx.x;
  const int b     = blockIdx.y;
  const int tid   = (int)threadIdx.x;
  const int w     = tid >> 6;
  const int w4    = w & 3;
  const int hf    = w >> 2;
  const int lane  = tid & 63;
  const int quad  = lane >> 4;
  const int nl    = lane & 15;
  const int row16 = tid >> 5;
  const int ci    = tid & 31;

  const int qbase    = qt * TQ;
  const size_t bLD   = (size_t)b * SL * HD;
  const size_t mbase = ((size_t)b * SL + qbase) * SL;

  __shared__ __align__(16) _Float16 S[TQ * SSTRIDE];   // 65.8 KB
  __shared__ float sinv_s[TQ];
  __shared__ float obuf[TQ][65];

  // ======== entry: stream masks for this thread's P1 slice, pack to u64 ========
  const int* dmr = DM  + mbase + (size_t)row16 * SL;
  const int* mkr = MMk + mbase + (size_t)row16 * SL;
  unsigned Wlo = 0, Whi = 0;
  {
    intx4 d0[4], d1[4], m0[4], m1[4];
    #pragma unroll
    for (int it = 0; it < 4; ++it) {
      const int c = it * 256 + ci * 8;
      d0[it] = __builtin_nontemporal_load((const intx4*)(dmr + c));
      d1[it] = __builtin_nontemporal_load((const intx4*)(dmr + c + 4));
      m0[it] = __builtin_nontemporal_load((const intx4*)(mkr + c));
      m1[it] = __builtin_nontemporal_load((const intx4*)(mkr + c + 4));
    }
    #pragma unroll
    for (int it = 0; it < 4; ++it) {
      unsigned by = 0;
      #pragma unroll
      for (int j = 0; j < 4; ++j) {
        by |= (unsigned)((d0[it][j] & ~m0[it][j]) & 1) << j;
        by |= (unsigned)((d1[it][j] & ~m1[it][j]) & 1) << (j + 4);
      }
      Wlo |= by << (it * 8);
    }
    #pragma unroll
    for (int it = 0; it < 4; ++it) {
      const int c = (it + 4) * 256 + ci * 8;
      d0[it] = __builtin_nontemporal_load((const intx4*)(dmr + c));
      d1[it] = __builtin_nontemporal_load((const intx4*)(dmr + c + 4));
      m0[it] = __builtin_nontemporal_load((const intx4*)(mkr + c));
      m1[it] = __builtin_nontemporal_load((const intx4*)(mkr + c + 4));
    }
    #pragma unroll
    for (int it = 0; it < 4; ++it) {
      unsigned by = 0;
      #pragma unroll
      for (int j = 0; j < 4; ++j) {
        by |= (unsigned)((d0[it][j] & ~m0[it][j]) & 1) << j;
        by |= (unsigned)((d1[it][j] & ~m1[it][j]) & 1) << (j + 4);
      }
      Whi |= by << (it * 8);
    }
  }

  // ---- Q fragments (A operand): lane holds Q[qbase + nl][quad*8+j (+32)]
  half8 aq0, aq1;
  {
    const float* qp = Q + bLD + (size_t)(qbase + nl) * HD + quad * 8;
    aq0 = load_frag_f32(qp);
    aq1 = load_frag_f32(qp + 32);
  }

  // ================= Phase A: QK^T -> S (each wave: 16 tiles) =================
  const int kt0 = hf * (NT / 2);
  #pragma unroll 2
  for (int kti = 0; kti < NT / 2; ++kti) {
    const int kt = kt0 + kti;
    half8 bk0, bk1;
    if constexpr (MODE >= 2) {
      const _Float16* kp = KH + bLD + (size_t)(kt * BK + w4 * 16 + nl) * HD + quad * 8;
      bk0 = *(const half8*)kp;
      bk1 = *(const half8*)(kp + 32);
    } else {
      const float* kp = K + bLD + (size_t)(kt * BK + w4 * 16 + nl) * HD + quad * 8;
      bk0 = load_frag_f32(kp);
      bk1 = load_frag_f32(kp + 32);
    }
    floatx4 acc = {0.f, 0.f, 0.f, 0.f};
    acc = __builtin_amdgcn_mfma_f32_16x16x32_f16(aq0, bk0, acc, 0, 0, 0);
    acc = __builtin_amdgcn_mfma_f32_16x16x32_f16(aq1, bk1, acc, 0, 0, 0);
    const int col = kt * BK + w4 * 16 + nl;
    #pragma unroll
    for (int r = 0; r < 4; ++r)
      S[(quad * 4 + r) * SSTRIDE + col] = (_Float16)(acc[r] * SC2);
  }
  __syncthreads();

  // ========== P1: mask bytes from registers + exp2 + sum, in-place ==========
  _Float16* srow = &S[row16 * SSTRIDE];
  float sum = 0.f;
  #pragma unroll
  for (int it = 0; it < 8; ++it) {
    const int c = it * 256 + ci * 8;
    const unsigned kb = ((it < 4 ? Wlo : Whi) >> ((it & 3) * 8)) & 0xFFu;
    half8 s8 = *(const half8*)(srow + c);
    half8 e8;
    #pragma unroll
    for (int j = 0; j < 4; ++j) {
      const float e0 = (kb & (1u << j))       ? __builtin_amdgcn_exp2f((float)s8[j])     : 0.f;
      const float e1 = (kb & (1u << (j + 4))) ? __builtin_amdgcn_exp2f((float)s8[j + 4]) : 0.f;
      sum += e0 + e1;
      e8[j]     = (_Float16)e0;   // e <= ~e^6, fp16 safe (validated earlier rounds)
      e8[j + 4] = (_Float16)e1;
    }
    *(half8*)(srow + c) = e8;     // unnormalized e for PV
  }
  #pragma unroll
  for (int off = 1; off < 32; off <<= 1)
    sum += __shfl_xor(sum, off, 64);   // 32 chunk-lanes of this row
  const float is = (sum > 0.f) ? 1.f / sum : 0.f;
  if (ci == 0) sinv_s[row16] = is;
  __syncthreads();   // all e in S + sinv_s visible before PV

  // ===== PV MFMA (16 tiles/wave) with interleaved normalized attn stores =====
  const float isr = sinv_s[row16];
  float* arow = Attn + mbase + (size_t)row16 * SL;
  floatx4 oacc = {0.f, 0.f, 0.f, 0.f};
  #pragma unroll
  for (int kti = 0; kti < NT / 2; ++kti) {
    const int kt = kt0 + kti;
    // A operand: lane holds E[m = nl][k = kt*64 + quad*8 + j (+32)]
    half8 ap0 = *(const half8*)(&S[nl * SSTRIDE + kt * BK + quad * 8]);
    half8 ap1 = *(const half8*)(&S[nl * SSTRIDE + kt * BK + quad * 8 + 32]);
    // B operand: lane holds V[k = kt*64 + quad*8 + j (+32)][n = w4*16 + nl]
    half8 bv0, bv1;
    if constexpr (MODE >= 2) {
      const _Float16* vp = VT + bLD + (size_t)(w4 * 16 + nl) * SL + kt * BK + quad * 8;
      bv0 = *(const half8*)vp;
      bv1 = *(const half8*)(vp + 32);
    } else {
      const float* vp = V + bLD + (size_t)(kt * BK + quad * 8) * HD + w4 * 16 + nl;
      #pragma unroll
      for (int j = 0; j < 8; ++j) {
        bv0[j] = (_Float16)vp[(size_t)j * HD];
        bv1[j] = (_Float16)vp[(size_t)(j + 32) * HD];
      }
    }
    oacc = __builtin_amdgcn_mfma_f32_16x16x32_f16(ap0, bv0, oacc, 0, 0, 0);
    oacc = __builtin_amdgcn_mfma_f32_16x16x32_f16(ap1, bv1, oacc, 0, 0, 0);
    // normalized attn store chunk every other tile: drains under MFMA latency
    if ((kti & 1) == 0) {
      const int c = (kti >> 1) * 256 + ci * 8;
      half8 e8v = *(const half8*)(srow + c);
      floatx4 o0, o1;
      #pragma unroll
      for (int j = 0; j < 4; ++j) {
        o0[j] = (float)e8v[j]     * isr;
        o1[j] = (float)e8v[j + 4] * isr;
      }
      __builtin_nontemporal_store(o0, (floatx4*)(arow + c));
      __builtin_nontemporal_store(o1, (floatx4*)(arow + c + 4));
    }
  }

  // ---- merge the two k-halves, normalize, store O
  if (hf == 1) {
    #pragma unroll
    for (int r = 0; r < 4; ++r)
      obuf[quad * 4 + r][w4 * 16 + nl] = oacc[r];
  }
  __syncthreads();
  if (hf == 0) {
    float* op = Out + ((size_t)b * SL + qbase) * HD;
    #pragma unroll
    for (int r = 0; r < 4; ++r) {
      const int row = quad * 4 + r;
      op[(size_t)row * HD + w4 * 16 + nl] =
          (oacc[r] + obuf[row][w4 * 16 + nl]) * sinv_s[row];
    }
  }
}

extern "C" void kernel_launch(void* const* d_in, const int* in_sizes, int n_in,
                              void* d_out, int out_size, void* d_ws, size_t ws_size,
                              hipStream_t stream) {
  const float* Q  = (const float*)d_in[0];
  const float* K  = (const float*)d_in[1];
  const float* V  = (const float*)d_in[2];
  const int* DM   = (const int*)d_in[3];
  const int* MMk  = (const int*)d_in[4];
  float* Out  = (float*)d_out;
  float* Attn = (float*)d_out + (size_t)NB * SL * HD;
  dim3 grid(SL / TQ, NB);

  const size_t needKV = (size_t)2 * NB * SL * HD * sizeof(_Float16);  // 8 MiB
  if (d_ws != nullptr && ws_size >= needKV) {
    _Float16* KH = (_Float16*)d_ws;
    _Float16* VT = KH + (size_t)NB * SL * HD;
    prep_kernel<<<dim3(512), 256, 0, stream>>>(K, V, KH, VT);
    attn_kernel<2><<<grid, 512, 0, stream>>>(Q, K, V, KH, VT, DM, MMk, Out, Attn);
  } else {
    attn_kernel<1><<<grid, 512, 0, stream>>>(Q, K, V, nullptr, nullptr, DM, MMk, Out, Attn);
  }
}